// Round 1
// 322.250 us; speedup vs baseline: 1.1187x; 1.1187x over previous
//
#include <hip/hip_runtime.h>

// SlotAttention MI355X (gfx950), round 7 = round 6 + fp16 xn cache.
// Theory: k_attn was VALU/DS-bound (~3x above HBM floor) because token-LN
// stats + affine fixup + stat transposes were recomputed every iteration on
// raw fp32 x. The token LN is iteration-invariant:
//   it 0 : read fp32 x, compute (x-m)*r once, STORE fp16 xn (67MB), light math
//   it1,2: read fp16 xn directly (67MB vs 134MB), light math
// Light math: logits[t][s] = xn_t . qw_s + beta_s   (no fixup, no transposes)
//             PRX[s][d]    = sum_t p * xn_t[d]      (selector-transpose PV)
//             alpha[s]     = sum_t p                 (delta/gamma eliminated)
// gru: upd[d] = lnw_in[d]*PRX[d]/alpha + lnb_in[d] ; then @Wv^T.

#define Nn 4096

typedef _Float16 f16;
typedef _Float16 f16x8 __attribute__((ext_vector_type(8)));
typedef _Float16 f16x4 __attribute__((ext_vector_type(4)));
typedef float    f32x4 __attribute__((ext_vector_type(4)));

#define MFMA16(a,b,c) __builtin_amdgcn_mfma_f32_16x16x16f16(a,b,c,0,0,0)
#define MFMA32(a,b,c) __builtin_amdgcn_mfma_f32_16x16x32_f16(a,b,c,0,0,0)
#define LGKM0() asm volatile("s_waitcnt lgkmcnt(0)" ::: "memory")

#if __has_builtin(__builtin_amdgcn_rcpf)
#define RCPF(x) __builtin_amdgcn_rcpf(x)
#else
#define RCPF(x) (1.0f/(x))
#endif

static __device__ __forceinline__ float dot4(f32x4 a, f32x4 b) {
  return a.x*b.x + a.y*b.y + a.z*b.z + a.w*b.w;
}

// ---------------------------------------------------------------- k_init ----
// blocks 0..55: slots = mu + exp(log_sigma)*noise (57344 floats, 1024/block)
// blocks 56..71: Mt[d][e] = 0.125 * sum_dd Wk[dd][d]*Wq[dd][e]  (fp32)
__global__ __launch_bounds__(256) void k_init(
    const float* __restrict__ noise, const float* __restrict__ mu,
    const float* __restrict__ ls, const float* __restrict__ Wq,
    const float* __restrict__ Wk, float* __restrict__ slots,
    float* __restrict__ Mt)
{
  int bk = blockIdx.x, t = threadIdx.x;
  if (bk < 56) {
    int i = bk*1024 + t*4;
    int d = i & 63;
    f32x4 nz = *(const f32x4*)(noise + i);
    f32x4 m4 = *(const f32x4*)(mu + d);
    f32x4 l4 = *(const f32x4*)(ls + d);
    f32x4 o;
    o.x = m4.x + expf(l4.x)*nz.x; o.y = m4.y + expf(l4.y)*nz.y;
    o.z = m4.z + expf(l4.z)*nz.z; o.w = m4.w + expf(l4.w)*nz.w;
    *(f32x4*)(slots + i) = o;
  } else {
    int idx = (bk-56)*256 + t;         // 0..4095
    int d = idx >> 6, e = idx & 63;
    float a = 0.f;
    for (int dd = 0; dd < 64; dd++)
      a += Wk[dd*64 + d] * Wq[dd*64 + e];
    Mt[idx] = a * 0.125f;              // fold scale = D^-0.5
  }
}

// ----------------------------------------------------------------- k_gru ----
// 224 blocks x 256 (4 waves, wave = one (b,s) row). Weight chunks (64x64)
// staged in LDS coalesced; per-lane dots read LDS rows (stride 68).
static __device__ __forceinline__ void stage_chunk(
    float (*Wl)[68], const float* __restrict__ src, int stride, int t)
{
  __syncthreads();                 // protect previous consumers of Wl
  int r = t >> 2, c4 = (t & 3) * 16;
  #pragma unroll
  for (int k = 0; k < 4; k++)
    *(f32x4*)&Wl[r][c4 + k*4] = *(const f32x4*)(src + (size_t)r*stride + c4 + k*4);
  __syncthreads();
}

static __device__ __forceinline__ float dot_row(
    float (*Wl)[68], int d, const float* v)
{
  float a = 0.f;
  #pragma unroll
  for (int jc = 0; jc < 16; jc++)
    a += dot4(*(const f32x4*)&Wl[d][jc*4], *(const f32x4*)(v + jc*4));
  return a;
}

__global__ __launch_bounds__(256) void k_gru(
    const float* __restrict__ part, const float* __restrict__ csp,
    const float* __restrict__ lnw_in, const float* __restrict__ lnb_in,
    const float* __restrict__ Wv,
    const float* __restrict__ W_ih, const float* __restrict__ W_hh,
    const float* __restrict__ b_ih, const float* __restrict__ b_hh,
    const float* __restrict__ lnm_w, const float* __restrict__ lnm_b,
    const float* __restrict__ W1, const float* __restrict__ b1,
    const float* __restrict__ W2, const float* __restrict__ b2,
    const float* __restrict__ lns_w, const float* __restrict__ lns_b,
    const float* __restrict__ Mt,
    float* __restrict__ slots, f16* __restrict__ qkpad,
    float* __restrict__ qkaux, int do_gru, int do_q)
{
  __shared__ __align__(16) float Wl[64][68];
  __shared__ __align__(16) float updv[4][64];
  __shared__ __align__(16) float u2v [4][64];
  __shared__ __align__(16) float prevv[4][64];
  __shared__ __align__(16) float mlnv[4][64];
  __shared__ __align__(16) float sn2 [4][64];
  __shared__ __align__(16) float hbuf[4][128];
  const int t = threadIdx.x, w = t >> 6, d = t & 63;
  const int wid = blockIdx.x*4 + w;             // 0..895
  const int b = wid / 7, s = wid - b*7;

  float out;
  if (do_gru) {
    // Y = sum of 8 chunk partials ; alpha from csp
    float Y = 0.f, alpha = 0.f;
    #pragma unroll
    for (int cx = 0; cx < 8; cx++) {
      Y     += part[(((size_t)b*8+cx)*8 + s)*64 + d];
      alpha += csp [(((size_t)b*8+cx)*8 + s)];
    }
    float upd_pre = lnw_in[d]*(Y/alpha) + lnb_in[d];
    float prev = slots[(size_t)wid*64 + d];
    updv[w][d] = upd_pre; prevv[w][d] = prev;
    LGKM0();

    stage_chunk(Wl, Wv, 64, t);
    u2v[w][d] = dot_row(Wl, d, updv[w]);        // updates = upd_pre @ Wv^T
    LGKM0();

    stage_chunk(Wl, W_ih,         64, t);
    float air = b_ih[d]     + dot_row(Wl, d, u2v[w]);
    stage_chunk(Wl, W_ih + 4096,  64, t);
    float aiz = b_ih[64+d]  + dot_row(Wl, d, u2v[w]);
    stage_chunk(Wl, W_ih + 8192,  64, t);
    float ain = b_ih[128+d] + dot_row(Wl, d, u2v[w]);
    stage_chunk(Wl, W_hh,         64, t);
    float ahr = b_hh[d]     + dot_row(Wl, d, prevv[w]);
    stage_chunk(Wl, W_hh + 4096,  64, t);
    float ahz = b_hh[64+d]  + dot_row(Wl, d, prevv[w]);
    stage_chunk(Wl, W_hh + 8192,  64, t);
    float ahn = b_hh[128+d] + dot_row(Wl, d, prevv[w]);

    float r = 1.f/(1.f + __expf(-(air+ahr)));
    float z = 1.f/(1.f + __expf(-(aiz+ahz)));
    float n = tanhf(ain + r*ahn);
    float hnew = (1.f - z)*n + z*prev;

    float s1 = hnew, s2 = hnew*hnew;
    #pragma unroll
    for (int m = 1; m < 64; m <<= 1) {
      s1 += __shfl_xor(s1, m, 64);
      s2 += __shfl_xor(s2, m, 64);
    }
    float mean = s1*(1.f/64.f), var = s2*(1.f/64.f) - mean*mean;
    float mln = (hnew - mean) * rsqrtf(var + 1e-5f) * lnm_w[d] + lnm_b[d];
    mlnv[w][d] = mln;
    LGKM0();

    stage_chunk(Wl, W1,        64, t);
    float h0 = fmaxf(b1[d]    + dot_row(Wl, d, mlnv[w]), 0.f);
    stage_chunk(Wl, W1 + 4096, 64, t);
    float h1 = fmaxf(b1[64+d] + dot_row(Wl, d, mlnv[w]), 0.f);
    hbuf[w][d] = h0; hbuf[w][64+d] = h1;
    LGKM0();

    stage_chunk(Wl, W2,      128, t);
    out = hnew + b2[d] + dot_row(Wl, d, hbuf[w]);
    stage_chunk(Wl, W2 + 64, 128, t);
    out += dot_row(Wl, d, hbuf[w] + 64);
    slots[(size_t)wid*64 + d] = out;
  } else {
    out = slots[(size_t)wid*64 + d];
  }

  if (do_q) {
    float s1 = out, s2 = out*out;
    #pragma unroll
    for (int m = 1; m < 64; m <<= 1) {
      s1 += __shfl_xor(s1, m, 64);
      s2 += __shfl_xor(s2, m, 64);
    }
    float mean = s1*(1.f/64.f), var = s2*(1.f/64.f) - mean*mean;
    float sv = (out - mean) * rsqrtf(var + 1e-5f) * lns_w[d] + lns_b[d];
    sn2[w][d] = sv;
    LGKM0();

    stage_chunk(Wl, Mt, 64, t);
    float qk = dot_row(Wl, d, sn2[w]);          // qk = sv @ Mt^T (scale folded)

    float qw = qk * lnw_in[d];                  // qkw for logits MFMA
    float bb = qk * lnb_in[d];                  // -> beta
    #pragma unroll
    for (int m = 1; m < 64; m <<= 1)
      bb += __shfl_xor(bb, m, 64);
    qkpad[((size_t)b*16 + s)*64 + d] = (f16)qw;
    if (d == 0) qkaux[(size_t)b*16 + s] = bb;
  }
}

// ---------------------------------------------------------------- k_attn ----
// grid (8,128): y=b, x=512-token chunk. 4 waves x 128 tokens (8 tiles of 16).
// first=1: read raw fp32 x, LN-normalize in-reg, store fp16 xn, light math.
// first=0: read fp16 xn directly, light math.
// Light math per tile: logits MFMA (+beta) -> softmax -> selector-transpose PV.
// Ends with NON-ATOMIC per-block partial stores (all 7x64 entries, strided).
static __device__ __forceinline__ void tile_common(
    f16x8 xf0, f16x8 xf1, const f16x8* qkB, float beta,
    f16x8 selLo, f16x8 selHi, bool valid, f32x4* acc, float& csump)
{
  const f32x4 zero4 = {0.f,0.f,0.f,0.f};
  f32x4 lg = zero4;
  lg = MFMA32(xf0, qkB[0], lg);
  lg = MFMA32(xf1, qkB[1], lg);
  float e[4], sm[4];
  #pragma unroll
  for (int j = 0; j < 4; j++) {
    float L = lg[j] + beta;
    e[j] = valid ? __expf(L) : 0.f;
    sm[j] = e[j];
  }
  #pragma unroll
  for (int m = 1; m < 16; m <<= 1)
    #pragma unroll
    for (int j = 0; j < 4; j++) sm[j] += __shfl_xor(sm[j], m, 64);
  f16x4 pp;
  #pragma unroll
  for (int j = 0; j < 4; j++) {
    float p = valid ? (e[j]*RCPF(sm[j]) + 1e-8f) : 0.f;
    csump += p;
    pp[j] = (f16)p;
  }
  #pragma unroll
  for (int nb = 0; nb < 4; nb++) {
    f32x4 tr = MFMA32(nb < 2 ? xf0 : xf1, (nb & 1) ? selHi : selLo, zero4);
    f16x4 xt; xt.x=(f16)tr.x; xt.y=(f16)tr.y; xt.z=(f16)tr.z; xt.w=(f16)tr.w;
    acc[nb] = MFMA16(pp, xt, acc[nb]);
  }
}

__global__ __launch_bounds__(256, 4) void k_attn(
    const float* __restrict__ x_in, const f16* __restrict__ qkpad,
    const float* __restrict__ qkaux, f16* __restrict__ xh,
    float* __restrict__ part, float* __restrict__ csp, int first)
{
  __shared__ __align__(16) float accb[4][8][64];
  __shared__ float ldsc[4][8];
  const int b = blockIdx.y, cx = blockIdx.x;
  const int tid = threadIdx.x;
  const int w = tid >> 6, lane = tid & 63, q = lane >> 4, c = lane & 15;

  f16x8 qkB[2];
  qkB[0] = *(const f16x8*)(qkpad + ((size_t)b*16 + c)*64 + q*8);
  qkB[1] = *(const f16x8*)(qkpad + ((size_t)b*16 + c)*64 + 32 + q*8);
  const float beta = qkaux[(size_t)b*16 + c];

  f16x8 selLo, selHi;
  #pragma unroll
  for (int j = 0; j < 8; j++) {
    selLo[j] = (f16)((( c>>3)    == q && (c&7) == j) ? 1.0f : 0.0f);
    selHi[j] = (f16)(((c>>3) + 2 == q && (c&7) == j) ? 1.0f : 0.0f);
  }

  const f32x4 zero4 = {0.f,0.f,0.f,0.f};
  f32x4 acc[4] = {zero4, zero4, zero4, zero4};
  float csump = 0.f;
  const size_t tok0 = (size_t)b*Nn + (size_t)cx*512 + (size_t)w*128;
  const bool valid = (c < 7);

  if (first) {
    // -------- heavy path: raw fp32 + per-token LN stats, write fp16 xn ----
    f32x4 nx[4];
    {
      const float* base = x_in + (tok0 + c)*64;
      nx[0] = *(const f32x4*)(base + q*8);
      nx[1] = *(const f32x4*)(base + q*8 + 4);
      nx[2] = *(const f32x4*)(base + 32 + q*8);
      nx[3] = *(const f32x4*)(base + 32 + q*8 + 4);
    }
    #pragma unroll
    for (int t = 0; t < 8; t++) {
      f32x4 xv[4];
      #pragma unroll
      for (int i = 0; i < 4; i++) xv[i] = nx[i];
      if (t < 7) {
        const float* base = x_in + (tok0 + (t+1)*16 + c)*64;
        nx[0] = *(const f32x4*)(base + q*8);
        nx[1] = *(const f32x4*)(base + q*8 + 4);
        nx[2] = *(const f32x4*)(base + 32 + q*8);
        nx[3] = *(const f32x4*)(base + 32 + q*8 + 4);
      }
      // token-c stats over 64 dims (4 lanes share token c)
      float sx  = (xv[0].x+xv[0].y+xv[0].z+xv[0].w) + (xv[1].x+xv[1].y+xv[1].z+xv[1].w)
                + (xv[2].x+xv[2].y+xv[2].z+xv[2].w) + (xv[3].x+xv[3].y+xv[3].z+xv[3].w);
      float sxx = dot4(xv[0],xv[0]) + dot4(xv[1],xv[1])
                + dot4(xv[2],xv[2]) + dot4(xv[3],xv[3]);
      sx  += __shfl_xor(sx, 16, 64);  sx  += __shfl_xor(sx, 32, 64);
      sxx += __shfl_xor(sxx, 16, 64); sxx += __shfl_xor(sxx, 32, 64);
      float mean = sx*(1.f/64.f);
      float rstd = rsqrtf(sxx*(1.f/64.f) - mean*mean + 1e-5f);
      float mr2 = mean * rstd;
      // normalize + cast to fp16 fragments (xn = x*rstd - mean*rstd)
      f16x8 xf0, xf1;
      #pragma unroll
      for (int j = 0; j < 4; j++) {
        xf0[j]   = (f16)(xv[0][j]*rstd - mr2);
        xf0[4+j] = (f16)(xv[1][j]*rstd - mr2);
        xf1[j]   = (f16)(xv[2][j]*rstd - mr2);
        xf1[4+j] = (f16)(xv[3][j]*rstd - mr2);
      }
      // persist xn for iterations 2,3
      f16* xo = xh + (tok0 + t*16 + c)*64;
      *(f16x8*)(xo + q*8)      = xf0;
      *(f16x8*)(xo + 32 + q*8) = xf1;

      tile_common(xf0, xf1, qkB, beta, selLo, selHi, valid, acc, csump);
    }
  } else {
    // -------- light path: read fp16 xn directly --------------------------
    f16x8 n0, n1;
    {
      const f16* base = xh + (tok0 + c)*64;
      n0 = *(const f16x8*)(base + q*8);
      n1 = *(const f16x8*)(base + 32 + q*8);
    }
    #pragma unroll
    for (int t = 0; t < 8; t++) {
      f16x8 xf0 = n0, xf1 = n1;
      if (t < 7) {
        const f16* base = xh + (tok0 + (t+1)*16 + c)*64;
        n0 = *(const f16x8*)(base + q*8);
        n1 = *(const f16x8*)(base + 32 + q*8);
      }
      tile_common(xf0, xf1, qkB, beta, selLo, selHi, valid, acc, csump);
    }
  }

  csump += __shfl_xor(csump, 16, 64); csump += __shfl_xor(csump, 32, 64);
  if (q == 0 && c < 7) ldsc[w][c] = csump;
  if (q < 2) {
    #pragma unroll
    for (int nb = 0; nb < 4; nb++)
      #pragma unroll
      for (int r = 0; r < 4; r++)
        accb[w][q*4 + r][nb*16 + c] = acc[nb][r];
  }
  __syncthreads();
  // 256 threads cover all 7*64=448 partial entries.
  for (int rr = tid; rr < 448; rr += 256) {
    int row = rr >> 6, dd = rr & 63;
    float v = accb[0][row][dd] + accb[1][row][dd]
            + accb[2][row][dd] + accb[3][row][dd];
    part[(((size_t)b*8 + cx)*8 + row)*64 + dd] = v;
  }
  if (tid < 7) {
    csp[(((size_t)b*8 + cx)*8 + tid)] =
        ldsc[0][tid] + ldsc[1][tid] + ldsc[2][tid] + ldsc[3][tid];
  }
}

// ----------------------------------------------------------- kernel_launch --
extern "C" void kernel_launch(void* const* d_in, const int* in_sizes, int n_in,
                              void* d_out, int out_size, void* d_ws, size_t ws_size,
                              hipStream_t stream) {
  const float* inputs  = (const float*)d_in[0];
  const float* noise   = (const float*)d_in[1];
  const float* ln_in_w = (const float*)d_in[2];
  const float* ln_in_b = (const float*)d_in[3];
  const float* ln_sl_w = (const float*)d_in[4];
  const float* ln_sl_b = (const float*)d_in[5];
  const float* ln_ml_w = (const float*)d_in[6];
  const float* ln_ml_b = (const float*)d_in[7];
  const float* mu   = (const float*)d_in[8];
  const float* ls   = (const float*)d_in[9];
  const float* Wq   = (const float*)d_in[10];
  const float* Wk   = (const float*)d_in[11];
  const float* Wv   = (const float*)d_in[12];
  const float* W_ih = (const float*)d_in[13];
  const float* W_hh = (const float*)d_in[14];
  const float* b_ih = (const float*)d_in[15];
  const float* b_hh = (const float*)d_in[16];
  const float* W1 = (const float*)d_in[17];
  const float* b1 = (const float*)d_in[18];
  const float* W2 = (const float*)d_in[19];
  const float* b2 = (const float*)d_in[20];

  float* slots = (float*)d_out;

  // workspace layout (bytes):
  // part  f32 [128][8][8][64]  @ 0        (2,097,152)
  // csp   f32 [128][8][8]      @ 2097152  (32,768)
  // qkpad f16 [128][16][64]    @ 2129920  (262,144)
  // qkaux f32 [128][16]        @ 2392064  (8,192)
  // Mt    f32 [64][64]         @ 2400256  (16,384)
  // xh    f16 [128][4096][64]  @ 2416640  (67,108,864)  -- 4KB aligned
  const size_t PART_OFF = 0;
  const size_t CSP_OFF  = PART_OFF + 2097152;
  const size_t QK_OFF   = CSP_OFF  + 32768;
  const size_t QA_OFF   = QK_OFF   + 262144;
  const size_t MT_OFF   = QA_OFF   + 8192;
  const size_t XH_OFF   = MT_OFF   + 16384;
  const size_t NEED     = XH_OFF   + 67108864;
  if (ws_size < NEED) return;

  char* ws = (char*)d_ws;
  float* part  = (float*)(ws + PART_OFF);
  float* csp   = (float*)(ws + CSP_OFF);
  f16*   qkpad = (f16*)  (ws + QK_OFF);
  float* qkaux = (float*)(ws + QA_OFF);
  float* Mt    = (float*)(ws + MT_OFF);
  f16*   xh    = (f16*)  (ws + XH_OFF);

  k_init<<<72, 256, 0, stream>>>(noise, mu, ls, Wq, Wk, slots, Mt);
  // initial q (no gru)
  k_gru<<<224, 256, 0, stream>>>(part, csp, ln_in_w, ln_in_b, Wv,
                                 W_ih, W_hh, b_ih, b_hh, ln_ml_w, ln_ml_b,
                                 W1, b1, W2, b2, ln_sl_w, ln_sl_b, Mt,
                                 slots, qkpad, qkaux, 0, 1);
  dim3 ga(8, 128);
  for (int it = 0; it < 3; it++) {
    k_attn<<<ga, 256, 0, stream>>>(inputs, qkpad, qkaux, xh, part, csp,
                                   it == 0 ? 1 : 0);
    k_gru<<<224, 256, 0, stream>>>(part, csp, ln_in_w, ln_in_b, Wv,
                                   W_ih, W_hh, b_ih, b_hh, ln_ml_w, ln_ml_b,
                                   W1, b1, W2, b2, ln_sl_w, ln_sl_b, Mt,
                                   slots, qkpad, qkaux, 1, it < 2 ? 1 : 0);
  }
}

// Round 2
// 318.032 us; speedup vs baseline: 1.1335x; 1.0133x over previous
//
#include <hip/hip_runtime.h>

// SlotAttention MI355X (gfx950), round 8.
// R7 post-mortem: k_attn near BW floor (light ~15us, heavy ~32us); remaining
// ~250us sits in 4x k_gru (1 block/CU, 1 wave/SIMD, 12 serial stage rounds,
// 24 barriers, 12 exposed L2 round-trips). Fix:
//  - k_gru: stage ALL phase-A weights (7x 64x64 chunks, 119KB LDS) in one
//    shot -> 1 barrier; stage phase-B weights (W1,W2,Mt) overlapped with the
//    GRU gate/LN register math -> 1 more barrier. 3 barriers total, ~2
//    latency exposures. Tree-accumulated dots.
//  - k_attn: grid.x 16 (4 tiles/wave), light path preloads all 4 tiles
//    (8 loads in flight/wave). part/csp now 16 chunks.

#define Nn 4096
#define NCH 16   // k_attn token chunks per batch

typedef _Float16 f16;
typedef _Float16 f16x8 __attribute__((ext_vector_type(8)));
typedef _Float16 f16x4 __attribute__((ext_vector_type(4)));
typedef float    f32x4 __attribute__((ext_vector_type(4)));

#define MFMA16(a,b,c) __builtin_amdgcn_mfma_f32_16x16x16f16(a,b,c,0,0,0)
#define MFMA32(a,b,c) __builtin_amdgcn_mfma_f32_16x16x32_f16(a,b,c,0,0,0)
#define LGKM0() asm volatile("s_waitcnt lgkmcnt(0)" ::: "memory")

#if __has_builtin(__builtin_amdgcn_rcpf)
#define RCPF(x) __builtin_amdgcn_rcpf(x)
#else
#define RCPF(x) (1.0f/(x))
#endif

static __device__ __forceinline__ float dot4(f32x4 a, f32x4 b) {
  return a.x*b.x + a.y*b.y + a.z*b.z + a.w*b.w;
}

// ---------------------------------------------------------------- k_init ----
// blocks 0..55: slots = mu + exp(log_sigma)*noise (57344 floats, 1024/block)
// blocks 56..71: Mt[d][e] = 0.125 * sum_dd Wk[dd][d]*Wq[dd][e]  (fp32)
__global__ __launch_bounds__(256) void k_init(
    const float* __restrict__ noise, const float* __restrict__ mu,
    const float* __restrict__ ls, const float* __restrict__ Wq,
    const float* __restrict__ Wk, float* __restrict__ slots,
    float* __restrict__ Mt)
{
  int bk = blockIdx.x, t = threadIdx.x;
  if (bk < 56) {
    int i = bk*1024 + t*4;
    int d = i & 63;
    f32x4 nz = *(const f32x4*)(noise + i);
    f32x4 m4 = *(const f32x4*)(mu + d);
    f32x4 l4 = *(const f32x4*)(ls + d);
    f32x4 o;
    o.x = m4.x + expf(l4.x)*nz.x; o.y = m4.y + expf(l4.y)*nz.y;
    o.z = m4.z + expf(l4.z)*nz.z; o.w = m4.w + expf(l4.w)*nz.w;
    *(f32x4*)(slots + i) = o;
  } else {
    int idx = (bk-56)*256 + t;         // 0..4095
    int d = idx >> 6, e = idx & 63;
    float a = 0.f;
    for (int dd = 0; dd < 64; dd++)
      a += Wk[dd*64 + d] * Wq[dd*64 + e];
    Mt[idx] = a * 0.125f;              // fold scale = D^-0.5
  }
}

// ----------------------------------------------------------------- k_gru ----
// 224 blocks x 256 (4 waves, wave = one (b,s) row).
// Phase A: stage 7 weight chunks (Wv, Wih r/z/n, Whh r/z/n) concurrently,
//          1 barrier, then all 7 GEMV dots.
// Phase B: stage W1(2), W2(2), Mt concurrently into freed WA[0..4] while the
//          gate/LN register math runs; 1 barrier; MLP dots; q-path dot.
static __device__ __forceinline__ void stageN(
    float (*dst)[68], const float* __restrict__ src, int stride, int sr, int sc)
{
  #pragma unroll
  for (int k = 0; k < 4; k++)
    *(f32x4*)&dst[sr][sc + k*4] = *(const f32x4*)(src + (size_t)sr*stride + sc + k*4);
}

static __device__ __forceinline__ float dot_row(
    const float (*Wl)[68], int d, const float* v)
{
  float a0 = 0.f, a1 = 0.f;
  #pragma unroll
  for (int jc = 0; jc < 16; jc += 2) {
    a0 += dot4(*(const f32x4*)&Wl[d][jc*4],     *(const f32x4*)(v + jc*4));
    a1 += dot4(*(const f32x4*)&Wl[d][jc*4 + 4], *(const f32x4*)(v + jc*4 + 4));
  }
  return a0 + a1;
}

__global__ __launch_bounds__(256) void k_gru(
    const float* __restrict__ part, const float* __restrict__ csp,
    const float* __restrict__ lnw_in, const float* __restrict__ lnb_in,
    const float* __restrict__ Wv,
    const float* __restrict__ W_ih, const float* __restrict__ W_hh,
    const float* __restrict__ b_ih, const float* __restrict__ b_hh,
    const float* __restrict__ lnm_w, const float* __restrict__ lnm_b,
    const float* __restrict__ W1, const float* __restrict__ b1,
    const float* __restrict__ W2, const float* __restrict__ b2,
    const float* __restrict__ lns_w, const float* __restrict__ lns_b,
    const float* __restrict__ Mt,
    float* __restrict__ slots, f16* __restrict__ qkpad,
    float* __restrict__ qkaux, int do_gru, int do_q)
{
  __shared__ __align__(16) float WA[7][64][68];      // 121,856 B
  __shared__ __align__(16) float updv[4][64];
  __shared__ __align__(16) float u2v [4][64];
  __shared__ __align__(16) float prevv[4][64];
  __shared__ __align__(16) float mlnv[4][64];
  __shared__ __align__(16) float sn2 [4][64];
  __shared__ __align__(16) float hbuf[4][128];
  const int t = threadIdx.x, w = t >> 6, d = t & 63;
  const int wid = blockIdx.x*4 + w;             // 0..895
  const int b = wid / 7, s = wid - b*7;
  const int sr = t >> 2, sc = (t & 3) * 16;     // staging row / col base

  float out;
  if (do_gru) {
    // ---- phase A: stage 7 chunks (one latency exposure) + row inputs ----
    {
      const float* srcs[7] = { Wv, W_ih, W_ih + 4096, W_ih + 8192,
                               W_hh, W_hh + 4096, W_hh + 8192 };
      #pragma unroll
      for (int i = 0; i < 7; i++) stageN(WA[i], srcs[i], 64, sr, sc);
    }
    float Y = 0.f, alpha = 0.f;
    #pragma unroll
    for (int cx = 0; cx < NCH; cx++) {
      Y     += part[(((size_t)b*NCH + cx)*8 + s)*64 + d];
      alpha += csp [ ((size_t)b*NCH + cx)*8 + s];
    }
    float upd_pre = lnw_in[d]*(Y/alpha) + lnb_in[d];
    float prev = slots[(size_t)wid*64 + d];
    updv[w][d] = upd_pre; prevv[w][d] = prev;
    __syncthreads();                            // staging + row bufs visible

    u2v[w][d] = dot_row(WA[0], d, updv[w]);     // updates = upd_pre @ Wv^T
    LGKM0();
    float air = b_ih[d]     + dot_row(WA[1], d, u2v[w]);
    float aiz = b_ih[64+d]  + dot_row(WA[2], d, u2v[w]);
    float ain = b_ih[128+d] + dot_row(WA[3], d, u2v[w]);
    float ahr = b_hh[d]     + dot_row(WA[4], d, prevv[w]);
    float ahz = b_hh[64+d]  + dot_row(WA[5], d, prevv[w]);
    float ahn = b_hh[128+d] + dot_row(WA[6], d, prevv[w]);
    __syncthreads();                            // all WA reads done

    // ---- phase B: stage W1/W2/Mt while gate+LN register math runs ----
    stageN(WA[0], W1,        64,  sr, sc);
    stageN(WA[1], W1 + 4096, 64,  sr, sc);
    stageN(WA[2], W2,        128, sr, sc);
    stageN(WA[3], W2 + 64,   128, sr, sc);
    stageN(WA[4], Mt,        64,  sr, sc);

    float r = 1.f/(1.f + __expf(-(air+ahr)));
    float z = 1.f/(1.f + __expf(-(aiz+ahz)));
    float n = tanhf(ain + r*ahn);
    float hnew = (1.f - z)*n + z*prev;

    float s1 = hnew, s2 = hnew*hnew;
    #pragma unroll
    for (int m = 1; m < 64; m <<= 1) {
      s1 += __shfl_xor(s1, m, 64);
      s2 += __shfl_xor(s2, m, 64);
    }
    float mean = s1*(1.f/64.f), var = s2*(1.f/64.f) - mean*mean;
    float mln = (hnew - mean) * rsqrtf(var + 1e-5f) * lnm_w[d] + lnm_b[d];
    mlnv[w][d] = mln;
    __syncthreads();                            // stage B + mlnv visible

    float h0 = fmaxf(b1[d]    + dot_row(WA[0], d, mlnv[w]), 0.f);
    float h1 = fmaxf(b1[64+d] + dot_row(WA[1], d, mlnv[w]), 0.f);
    hbuf[w][d] = h0; hbuf[w][64+d] = h1;
    LGKM0();
    out = hnew + b2[d] + dot_row(WA[2], d, hbuf[w])
                       + dot_row(WA[3], d, hbuf[w] + 64);
    slots[(size_t)wid*64 + d] = out;
  } else {
    stageN(WA[4], Mt, 64, sr, sc);              // q-path only needs Mt
    out = slots[(size_t)wid*64 + d];
    __syncthreads();
  }

  if (do_q) {
    float s1 = out, s2 = out*out;
    #pragma unroll
    for (int m = 1; m < 64; m <<= 1) {
      s1 += __shfl_xor(s1, m, 64);
      s2 += __shfl_xor(s2, m, 64);
    }
    float mean = s1*(1.f/64.f), var = s2*(1.f/64.f) - mean*mean;
    float sv = (out - mean) * rsqrtf(var + 1e-5f) * lns_w[d] + lns_b[d];
    sn2[w][d] = sv;
    LGKM0();

    float qk = dot_row(WA[4], d, sn2[w]);       // qk = sv @ Mt^T (scale folded)

    float qw = qk * lnw_in[d];                  // qkw for logits MFMA
    float bb = qk * lnb_in[d];                  // -> beta
    #pragma unroll
    for (int m = 1; m < 64; m <<= 1)
      bb += __shfl_xor(bb, m, 64);
    qkpad[((size_t)b*16 + s)*64 + d] = (f16)qw;
    if (d == 0) qkaux[(size_t)b*16 + s] = bb;
  }
}

// ---------------------------------------------------------------- k_attn ----
// grid (16,128): y=b, x=256-token chunk. 4 waves x 64 tokens (4 tiles of 16).
// first=1: read raw fp32 x, LN-normalize in-reg, store fp16 xn, light math.
// first=0: preload all 4 tiles of fp16 xn (8 loads in flight), light math.
static __device__ __forceinline__ void tile_common(
    f16x8 xf0, f16x8 xf1, const f16x8* qkB, float beta,
    f16x8 selLo, f16x8 selHi, bool valid, f32x4* acc, float& csump)
{
  const f32x4 zero4 = {0.f,0.f,0.f,0.f};
  f32x4 lg = zero4;
  lg = MFMA32(xf0, qkB[0], lg);
  lg = MFMA32(xf1, qkB[1], lg);
  float e[4], sm[4];
  #pragma unroll
  for (int j = 0; j < 4; j++) {
    float L = lg[j] + beta;
    e[j] = valid ? __expf(L) : 0.f;
    sm[j] = e[j];
  }
  #pragma unroll
  for (int m = 1; m < 16; m <<= 1)
    #pragma unroll
    for (int j = 0; j < 4; j++) sm[j] += __shfl_xor(sm[j], m, 64);
  f16x4 pp;
  #pragma unroll
  for (int j = 0; j < 4; j++) {
    float p = valid ? (e[j]*RCPF(sm[j]) + 1e-8f) : 0.f;
    csump += p;
    pp[j] = (f16)p;
  }
  #pragma unroll
  for (int nb = 0; nb < 4; nb++) {
    f32x4 tr = MFMA32(nb < 2 ? xf0 : xf1, (nb & 1) ? selHi : selLo, zero4);
    f16x4 xt; xt.x=(f16)tr.x; xt.y=(f16)tr.y; xt.z=(f16)tr.z; xt.w=(f16)tr.w;
    acc[nb] = MFMA16(pp, xt, acc[nb]);
  }
}

__global__ __launch_bounds__(256, 4) void k_attn(
    const float* __restrict__ x_in, const f16* __restrict__ qkpad,
    const float* __restrict__ qkaux, f16* __restrict__ xh,
    float* __restrict__ part, float* __restrict__ csp, int first)
{
  __shared__ __align__(16) float accb[4][8][64];
  __shared__ float ldsc[4][8];
  const int b = blockIdx.y, cx = blockIdx.x;
  const int tid = threadIdx.x;
  const int w = tid >> 6, lane = tid & 63, q = lane >> 4, c = lane & 15;

  f16x8 qkB[2];
  qkB[0] = *(const f16x8*)(qkpad + ((size_t)b*16 + c)*64 + q*8);
  qkB[1] = *(const f16x8*)(qkpad + ((size_t)b*16 + c)*64 + 32 + q*8);
  const float beta = qkaux[(size_t)b*16 + c];

  f16x8 selLo, selHi;
  #pragma unroll
  for (int j = 0; j < 8; j++) {
    selLo[j] = (f16)((( c>>3)    == q && (c&7) == j) ? 1.0f : 0.0f);
    selHi[j] = (f16)(((c>>3) + 2 == q && (c&7) == j) ? 1.0f : 0.0f);
  }

  const f32x4 zero4 = {0.f,0.f,0.f,0.f};
  f32x4 acc[4] = {zero4, zero4, zero4, zero4};
  float csump = 0.f;
  const size_t tok0 = (size_t)b*Nn + (size_t)cx*256 + (size_t)w*64;
  const bool valid = (c < 7);

  if (first) {
    // -------- heavy path: raw fp32 + per-token LN stats, write fp16 xn ----
    f32x4 nx[4];
    {
      const float* base = x_in + (tok0 + c)*64;
      nx[0] = *(const f32x4*)(base + q*8);
      nx[1] = *(const f32x4*)(base + q*8 + 4);
      nx[2] = *(const f32x4*)(base + 32 + q*8);
      nx[3] = *(const f32x4*)(base + 32 + q*8 + 4);
    }
    #pragma unroll
    for (int t = 0; t < 4; t++) {
      f32x4 xv[4];
      #pragma unroll
      for (int i = 0; i < 4; i++) xv[i] = nx[i];
      if (t < 3) {
        const float* base = x_in + (tok0 + (t+1)*16 + c)*64;
        nx[0] = *(const f32x4*)(base + q*8);
        nx[1] = *(const f32x4*)(base + q*8 + 4);
        nx[2] = *(const f32x4*)(base + 32 + q*8);
        nx[3] = *(const f32x4*)(base + 32 + q*8 + 4);
      }
      // token-c stats over 64 dims (4 lanes share token c)
      float sx  = (xv[0].x+xv[0].y+xv[0].z+xv[0].w) + (xv[1].x+xv[1].y+xv[1].z+xv[1].w)
                + (xv[2].x+xv[2].y+xv[2].z+xv[2].w) + (xv[3].x+xv[3].y+xv[3].z+xv[3].w);
      float sxx = dot4(xv[0],xv[0]) + dot4(xv[1],xv[1])
                + dot4(xv[2],xv[2]) + dot4(xv[3],xv[3]);
      sx  += __shfl_xor(sx, 16, 64);  sx  += __shfl_xor(sx, 32, 64);
      sxx += __shfl_xor(sxx, 16, 64); sxx += __shfl_xor(sxx, 32, 64);
      float mean = sx*(1.f/64.f);
      float rstd = rsqrtf(sxx*(1.f/64.f) - mean*mean + 1e-5f);
      float mr2 = mean * rstd;
      // normalize + cast to fp16 fragments (xn = x*rstd - mean*rstd)
      f16x8 xf0, xf1;
      #pragma unroll
      for (int j = 0; j < 4; j++) {
        xf0[j]   = (f16)(xv[0][j]*rstd - mr2);
        xf0[4+j] = (f16)(xv[1][j]*rstd - mr2);
        xf1[j]   = (f16)(xv[2][j]*rstd - mr2);
        xf1[4+j] = (f16)(xv[3][j]*rstd - mr2);
      }
      // persist xn for iterations 2,3
      f16* xo = xh + (tok0 + t*16 + c)*64;
      *(f16x8*)(xo + q*8)      = xf0;
      *(f16x8*)(xo + 32 + q*8) = xf1;

      tile_common(xf0, xf1, qkB, beta, selLo, selHi, valid, acc, csump);
    }
  } else {
    // -------- light path: preload ALL 4 tiles of fp16 xn ------------------
    f16x8 L0[4], L1[4];
    #pragma unroll
    for (int t = 0; t < 4; t++) {
      const f16* base = xh + (tok0 + t*16 + c)*64;
      L0[t] = *(const f16x8*)(base + q*8);
      L1[t] = *(const f16x8*)(base + 32 + q*8);
    }
    #pragma unroll
    for (int t = 0; t < 4; t++)
      tile_common(L0[t], L1[t], qkB, beta, selLo, selHi, valid, acc, csump);
  }

  csump += __shfl_xor(csump, 16, 64); csump += __shfl_xor(csump, 32, 64);
  if (q == 0 && c < 7) ldsc[w][c] = csump;
  if (q < 2) {
    #pragma unroll
    for (int nb = 0; nb < 4; nb++)
      #pragma unroll
      for (int r = 0; r < 4; r++)
        accb[w][q*4 + r][nb*16 + c] = acc[nb][r];
  }
  __syncthreads();
  // 256 threads cover all 7*64=448 partial entries.
  for (int rr = tid; rr < 448; rr += 256) {
    int row = rr >> 6, dd = rr & 63;
    float v = accb[0][row][dd] + accb[1][row][dd]
            + accb[2][row][dd] + accb[3][row][dd];
    part[(((size_t)b*NCH + cx)*8 + row)*64 + dd] = v;
  }
  if (tid < 7) {
    csp[((size_t)b*NCH + cx)*8 + tid] =
        ldsc[0][tid] + ldsc[1][tid] + ldsc[2][tid] + ldsc[3][tid];
  }
}

// ----------------------------------------------------------- kernel_launch --
extern "C" void kernel_launch(void* const* d_in, const int* in_sizes, int n_in,
                              void* d_out, int out_size, void* d_ws, size_t ws_size,
                              hipStream_t stream) {
  const float* inputs  = (const float*)d_in[0];
  const float* noise   = (const float*)d_in[1];
  const float* ln_in_w = (const float*)d_in[2];
  const float* ln_in_b = (const float*)d_in[3];
  const float* ln_sl_w = (const float*)d_in[4];
  const float* ln_sl_b = (const float*)d_in[5];
  const float* ln_ml_w = (const float*)d_in[6];
  const float* ln_ml_b = (const float*)d_in[7];
  const float* mu   = (const float*)d_in[8];
  const float* ls   = (const float*)d_in[9];
  const float* Wq   = (const float*)d_in[10];
  const float* Wk   = (const float*)d_in[11];
  const float* Wv   = (const float*)d_in[12];
  const float* W_ih = (const float*)d_in[13];
  const float* W_hh = (const float*)d_in[14];
  const float* b_ih = (const float*)d_in[15];
  const float* b_hh = (const float*)d_in[16];
  const float* W1 = (const float*)d_in[17];
  const float* b1 = (const float*)d_in[18];
  const float* W2 = (const float*)d_in[19];
  const float* b2 = (const float*)d_in[20];

  float* slots = (float*)d_out;

  // workspace layout (bytes):
  // part  f32 [128][16][8][64] @ 0        (4,194,304)
  // csp   f32 [128][16][8]     @ 4194304  (65,536)
  // qkpad f16 [128][16][64]    @ 4259840  (262,144)
  // qkaux f32 [128][16]        @ 4521984  (8,192)
  // Mt    f32 [64][64]         @ 4530176  (16,384)
  // xh    f16 [128][4096][64]  @ 4546560  (67,108,864)
  const size_t PART_OFF = 0;
  const size_t CSP_OFF  = PART_OFF + 4194304;
  const size_t QK_OFF   = CSP_OFF  + 65536;
  const size_t QA_OFF   = QK_OFF   + 262144;
  const size_t MT_OFF   = QA_OFF   + 8192;
  const size_t XH_OFF   = MT_OFF   + 16384;
  const size_t NEED     = XH_OFF   + 67108864;
  if (ws_size < NEED) return;

  char* ws = (char*)d_ws;
  float* part  = (float*)(ws + PART_OFF);
  float* csp   = (float*)(ws + CSP_OFF);
  f16*   qkpad = (f16*)  (ws + QK_OFF);
  float* qkaux = (float*)(ws + QA_OFF);
  float* Mt    = (float*)(ws + MT_OFF);
  f16*   xh    = (f16*)  (ws + XH_OFF);

  k_init<<<72, 256, 0, stream>>>(noise, mu, ls, Wq, Wk, slots, Mt);
  // initial q (no gru)
  k_gru<<<224, 256, 0, stream>>>(part, csp, ln_in_w, ln_in_b, Wv,
                                 W_ih, W_hh, b_ih, b_hh, ln_ml_w, ln_ml_b,
                                 W1, b1, W2, b2, ln_sl_w, ln_sl_b, Mt,
                                 slots, qkpad, qkaux, 0, 1);
  dim3 ga(NCH, 128);
  for (int it = 0; it < 3; it++) {
    k_attn<<<ga, 256, 0, stream>>>(inputs, qkpad, qkaux, xh, part, csp,
                                   it == 0 ? 1 : 0);
    k_gru<<<224, 256, 0, stream>>>(part, csp, ln_in_w, ln_in_b, Wv,
                                   W_ih, W_hh, b_ih, b_hh, ln_ml_w, ln_ml_b,
                                   W1, b1, W2, b2, ln_sl_w, ln_sl_b, Mt,
                                   slots, qkpad, qkaux, 1, it < 2 ? 1 : 0);
  }
}